// Round 2
// baseline (472.437 us; speedup 1.0000x reference)
//
#include <hip/hip_runtime.h>
#include <hip/hip_bf16.h>

typedef _Float16 half8 __attribute__((ext_vector_type(8)));
typedef _Float16 half4 __attribute__((ext_vector_type(4)));
typedef float f32x4 __attribute__((ext_vector_type(4)));

#define NTOK 4096
#define CDIM 256

#define GLD_LDS16(g, l) __builtin_amdgcn_global_load_lds( \
    (const __attribute__((address_space(1))) void*)(g), \
    (__attribute__((address_space(3))) void*)(l), 16, 0, 0)

// ---------------------------------------------------------------------------
// Kernel 1: projections (unchanged from passing version).
// Q,K token-major [bs][N][C] fp16; V channel-major [bs][C][N] fp16. bs=b*2+s.
// ---------------------------------------------------------------------------
__global__ __launch_bounds__(256, 2) void proj_kernel(
    const float* __restrict__ x1, const float* __restrict__ x2,
    const float* __restrict__ Wq, const float* __restrict__ bq,
    const float* __restrict__ Wk, const float* __restrict__ bk,
    const float* __restrict__ Wv, const float* __restrict__ bv,
    _Float16* __restrict__ Qh, _Float16* __restrict__ Kh,
    _Float16* __restrict__ Vt)
{
    __shared__ __align__(16) _Float16 Xl[64][264];
    __shared__ __align__(16) _Float16 Wl[64][264];
    __shared__ __align__(16) _Float16 Ol[64][68];

    const int t = threadIdx.x;
    const int lane = t & 63;
    const int w = t >> 6;
    const int bs = blockIdx.x >> 6;
    const int ntile = blockIdx.x & 63;
    const int n0 = ntile * 64;
    const int s = bs & 1, b = bs >> 1;

    const float* x = (s ? x2 : x1) + (size_t)b * CDIM * NTOK;

#pragma unroll
    for (int i = 0; i < 16; i++) {
        int id = t + 256 * i;
        int c = id >> 4, n4 = (id & 15) * 4;
        float4 v = *(const float4*)(x + (size_t)c * NTOK + n0 + n4);
        Xl[n4 + 0][c] = (_Float16)v.x;
        Xl[n4 + 1][c] = (_Float16)v.y;
        Xl[n4 + 2][c] = (_Float16)v.z;
        Xl[n4 + 3][c] = (_Float16)v.w;
    }

    for (int proj = 0; proj < 3; proj++) {
        const float* Wp = proj == 0 ? Wq : (proj == 1 ? Wk : Wv);
        const float* bp = proj == 0 ? bq : (proj == 1 ? bk : bv);
        for (int dt = 0; dt < 4; dt++) {
            const int d0 = dt * 64;
            __syncthreads();
#pragma unroll
            for (int i = 0; i < 16; i++) {
                int id = t + 256 * i;
                int d = id >> 6, c4 = (id & 63) * 4;
                float4 v = *(const float4*)(Wp + (size_t)(d0 + d) * CDIM + c4);
                half4 h = { (_Float16)v.x, (_Float16)v.y, (_Float16)v.z, (_Float16)v.w };
                *(half4*)&Wl[d][c4] = h;
            }
            __syncthreads();

            f32x4 acc[4];
            const f32x4 fz = {0.f, 0.f, 0.f, 0.f};
#pragma unroll
            for (int nt = 0; nt < 4; nt++) acc[nt] = fz;
#pragma unroll
            for (int cc = 0; cc < 8; cc++) {
                half8 wf = *(const half8*)&Wl[16 * w + (lane & 15)][cc * 32 + (lane >> 4) * 8];
#pragma unroll
                for (int nt = 0; nt < 4; nt++) {
                    half8 xf = *(const half8*)&Xl[nt * 16 + (lane & 15)][cc * 32 + (lane >> 4) * 8];
                    acc[nt] = __builtin_amdgcn_mfma_f32_16x16x32_f16(wf, xf, acc[nt], 0, 0, 0);
                }
            }
#pragma unroll
            for (int r = 0; r < 4; r++) {
                float bias = bp[d0 + 16 * w + (lane >> 4) * 4 + r];
#pragma unroll
                for (int nt = 0; nt < 4; nt++) {
                    _Float16 hv = (_Float16)(acc[nt][r] + bias);
                    if (proj < 2) Ol[nt * 16 + (lane & 15)][16 * w + (lane >> 4) * 4 + r] = hv;
                    else          Ol[16 * w + (lane >> 4) * 4 + r][nt * 16 + (lane & 15)] = hv;
                }
            }
            __syncthreads();
            _Float16* dst;
            size_t stride;
            if (proj == 0)      { dst = Qh + ((size_t)bs * NTOK + n0) * CDIM + d0; stride = CDIM; }
            else if (proj == 1) { dst = Kh + ((size_t)bs * NTOK + n0) * CDIM + d0; stride = CDIM; }
            else                { dst = Vt + ((size_t)bs * CDIM + d0) * NTOK + n0; stride = NTOK; }
#pragma unroll
            for (int i = 0; i < 4; i++) {
                int id = t + 256 * i;
                int row = id >> 4, c4 = (id & 15) * 4;
                *(half4*)(dst + (size_t)row * stride + c4) = *(const half4*)&Ol[row][c4];
            }
        }
    }
}

// ---------------------------------------------------------------------------
// Kernel 2: flash attention v2.
// Block = 128 q-rows (4 waves x 32 rows), 256 blocks, bs = blockIdx & 7.
// K/V double-buffered in LDS via global_load_lds (linear dest, pre-swizzled
// source); all ds_reads apply byte ^= ((row&7)<<4).
// LDS: Kb[2] 64KB | Vb[2] 64KB | P 16KB = 144KB -> 1 block/CU.
// ---------------------------------------------------------------------------
__global__ __launch_bounds__(256, 1) void flash_kernel(
    const _Float16* __restrict__ Qh, const _Float16* __restrict__ Kh,
    const _Float16* __restrict__ Vt, float* __restrict__ out)
{
    __shared__ __align__(16) char smem[147456];
    char* const Pb = smem + 131072;          // [128 n][64 m] halfs, swizzled
    float* const Olp = (float*)smem;         // epilogue reuse: [256 c][132]

    const int t = threadIdx.x, lane = t & 63, w = t >> 6;
    const int bs = blockIdx.x & 7;           // XCD-affine: one bs per XCD
    const int qt = blockIdx.x >> 3;          // 0..31
    const int n0 = qt * 128;
    const int s = bs & 1, b = bs >> 1;

    // Q fragments: wave w owns rows n0 + w*32 .. +31 (2 n-subtiles of 16)
    half8 qf[2][8];
#pragma unroll
    for (int nt = 0; nt < 2; nt++) {
        const _Float16* qp = Qh + ((size_t)bs * NTOK + n0 + w * 32 + nt * 16 + (lane & 15)) * CDIM
                                + (lane >> 4) * 8;
#pragma unroll
        for (int cc = 0; cc < 8; cc++) qf[nt][cc] = *(const half8*)(qp + cc * 32);
    }

    const int bsK = b * 2 + (s ^ 1);
    const uint4* const Ksrc = (const uint4*)(Kh + (size_t)bsK * NTOK * CDIM);
    const uint4* const Vsrc = (const uint4*)(Vt + (size_t)bs * CDIM * NTOK);

    float m_run[2][4], l_run[2][4];
    f32x4 Oacc[2][16];
    const f32x4 fz = {0.f, 0.f, 0.f, 0.f};
#pragma unroll
    for (int nt = 0; nt < 2; nt++) {
#pragma unroll
        for (int r = 0; r < 4; r++) { m_run[nt][r] = -1e30f; l_run[nt][r] = 0.f; }
#pragma unroll
        for (int ct = 0; ct < 16; ct++) Oacc[nt][ct] = fz;
    }

    // ---- staging: K tile 2048 chunks, V tile 2048 chunks; wave w does 512+512
    auto stage = [&](int buf, int kt) {
        const int m0 = kt * 64;
        char* kdst = smem + buf * 32768 + w * 8192;
        char* vdst = smem + 65536 + buf * 32768 + w * 8192;
#pragma unroll
        for (int i = 0; i < 8; i++) {
            int id = w * 512 + i * 64 + lane;
            int m = id >> 5, pc = id & 31;                    // K: row m, phys chunk pc
            GLD_LDS16(Ksrc + (size_t)(m0 + m) * 32 + (pc ^ (m & 7)), kdst + i * 1024);
        }
#pragma unroll
        for (int i = 0; i < 8; i++) {
            int id = w * 512 + i * 64 + lane;
            int c = id >> 3, pc = id & 7;                     // V: row c, phys chunk pc
            GLD_LDS16(Vsrc + (size_t)c * (NTOK / 8) + (m0 >> 3) + (pc ^ (c & 7)), vdst + i * 1024);
        }
    };

    stage(0, 0);
    __syncthreads();   // drains vmcnt -> tile 0 ready

    for (int kt = 0; kt < 64; kt++) {
        const int cur = kt & 1;
        if (kt < 63) stage(cur ^ 1, kt + 1);   // async prefetch, drains at barrier below

        const char* Kbase = smem + cur * 32768;
        const char* Vbase = smem + 65536 + cur * 32768;

        // ---- S = Q K^T : 2 n-subtiles share every K fragment
        f32x4 sf[2][4];
#pragma unroll
        for (int nt = 0; nt < 2; nt++)
#pragma unroll
            for (int mt = 0; mt < 4; mt++) sf[nt][mt] = fz;
#pragma unroll
        for (int cc = 0; cc < 8; cc++) {
#pragma unroll
            for (int mt = 0; mt < 4; mt++) {
                int row = mt * 16 + (lane & 15);
                half8 kf = *(const half8*)(Kbase + row * 512
                            + (((cc * 4 + (lane >> 4)) ^ (row & 7)) << 4));
                sf[0][mt] = __builtin_amdgcn_mfma_f32_16x16x32_f16(qf[0][cc], kf, sf[0][mt], 0, 0, 0);
                sf[1][mt] = __builtin_amdgcn_mfma_f32_16x16x32_f16(qf[1][cc], kf, sf[1][mt], 0, 0, 0);
            }
        }

        // ---- online softmax (16-lane row groups)
        float scale[2][4];
#pragma unroll
        for (int nt = 0; nt < 2; nt++) {
#pragma unroll
            for (int r = 0; r < 4; r++) {
                float mx = fmaxf(fmaxf(sf[nt][0][r], sf[nt][1][r]), fmaxf(sf[nt][2][r], sf[nt][3][r]));
                mx = fmaxf(mx, __shfl_xor(mx, 1));
                mx = fmaxf(mx, __shfl_xor(mx, 2));
                mx = fmaxf(mx, __shfl_xor(mx, 4));
                mx = fmaxf(mx, __shfl_xor(mx, 8));
                float nm = fmaxf(m_run[nt][r], mx);
                scale[nt][r] = __expf(m_run[nt][r] - nm);
                m_run[nt][r] = nm;
                float sum = 0.f;
#pragma unroll
                for (int mt = 0; mt < 4; mt++) {
                    float p = __expf(sf[nt][mt][r] - nm);
                    sf[nt][mt][r] = p;
                    sum += p;
                }
                sum += __shfl_xor(sum, 1);
                sum += __shfl_xor(sum, 2);
                sum += __shfl_xor(sum, 4);
                sum += __shfl_xor(sum, 8);
                l_run[nt][r] = l_run[nt][r] * scale[nt][r] + sum;
            }
        }

        // ---- P -> LDS (wave-private rows, swizzled scalar stores)
#pragma unroll
        for (int nt = 0; nt < 2; nt++) {
#pragma unroll
            for (int mt = 0; mt < 4; mt++) {
#pragma unroll
                for (int r = 0; r < 4; r++) {
                    int row = w * 32 + nt * 16 + (lane >> 4) * 4 + r;
                    int byteoff = row * 128 + (mt * 16 + (lane & 15)) * 2;
                    *(_Float16*)(Pb + (byteoff ^ ((row & 7) << 4))) = (_Float16)sf[nt][mt][r];
                }
            }
        }

        // ---- rescale O
#pragma unroll
        for (int nt = 0; nt < 2; nt++)
#pragma unroll
            for (int ct = 0; ct < 16; ct++)
#pragma unroll
                for (int r = 0; r < 4; r++) Oacc[nt][ct][r] *= scale[nt][r];

        // ---- O += P V : 2 n-subtiles share every V fragment
#pragma unroll
        for (int kc = 0; kc < 2; kc++) {
            half8 pa[2];
#pragma unroll
            for (int nt = 0; nt < 2; nt++) {
                int row = w * 32 + nt * 16 + (lane & 15);
                pa[nt] = *(const half8*)(Pb + ((row * 128 + kc * 64 + (lane >> 4) * 16)
                                               ^ ((row & 7) << 4)));
            }
#pragma unroll
            for (int ct = 0; ct < 16; ct++) {
                int c = ct * 16 + (lane & 15);
                half8 vf = *(const half8*)(Vbase + c * 128
                            + (((kc * 4 + (lane >> 4)) ^ (c & 7)) << 4));
                Oacc[0][ct] = __builtin_amdgcn_mfma_f32_16x16x32_f16(pa[0], vf, Oacc[0][ct], 0, 0, 0);
                Oacc[1][ct] = __builtin_amdgcn_mfma_f32_16x16x32_f16(pa[1], vf, Oacc[1][ct], 0, 0, 0);
            }
        }

        __syncthreads();   // waves done with buf[cur]; prefetch of buf[cur^1] drained
    }

    // ---- epilogue: transpose through LDS for coalesced [c][n] fp32 stores
    f32x4 inv[2];
#pragma unroll
    for (int nt = 0; nt < 2; nt++)
#pragma unroll
        for (int r = 0; r < 4; r++) inv[nt][r] = 1.0f / l_run[nt][r];
#pragma unroll
    for (int nt = 0; nt < 2; nt++) {
#pragma unroll
        for (int ct = 0; ct < 16; ct++) {
            int c = ct * 16 + (lane & 15);
            f32x4 v = Oacc[nt][ct] * inv[nt];
            *(f32x4*)(Olp + (size_t)c * 132 + w * 32 + nt * 16 + (lane >> 4) * 4) = v;
        }
    }
    __syncthreads();
    float* obase = out + (size_t)(s * 4 + b) * CDIM * NTOK + n0;
#pragma unroll
    for (int i = 0; i < 32; i++) {
        int id = t + 256 * i;
        int c = id >> 5, n4 = (id & 31) * 4;
        *(float4*)(obase + (size_t)c * NTOK + n4) = *(const float4*)(Olp + (size_t)c * 132 + n4);
    }
}

// ---------------------------------------------------------------------------
extern "C" void kernel_launch(void* const* d_in, const int* in_sizes, int n_in,
                              void* d_out, int out_size, void* d_ws, size_t ws_size,
                              hipStream_t stream) {
    const float* x1 = (const float*)d_in[0];
    const float* x2 = (const float*)d_in[1];
    const float* Wq = (const float*)d_in[2];
    const float* bq = (const float*)d_in[3];
    const float* Wk = (const float*)d_in[4];
    const float* bk = (const float*)d_in[5];
    const float* Wv = (const float*)d_in[6];
    const float* bv = (const float*)d_in[7];

    _Float16* Qh = (_Float16*)d_ws;
    _Float16* Kh = Qh + (size_t)8 * NTOK * CDIM;
    _Float16* Vt = Kh + (size_t)8 * NTOK * CDIM;

    proj_kernel<<<dim3(512), dim3(256), 0, stream>>>(x1, x2, Wq, bq, Wk, bk, Wv, bv, Qh, Kh, Vt);
    flash_kernel<<<dim3(256), dim3(256), 0, stream>>>(Qh, Kh, Vt, (float*)d_out);
}